// Round 6
// baseline (387.899 us; speedup 1.0000x reference)
//
#include <hip/hip_runtime.h>
#include <hip/hip_bf16.h>
#include <math.h>

#define M_TOT 4096
#define K_TOT 1024
#define V_TOT 32000
#define NKT 32  // K-tiles of BK=32

typedef short short8 __attribute__((ext_vector_type(8)));
typedef float f32x4 __attribute__((ext_vector_type(4)));

__device__ __forceinline__ void gload_lds16(const void* g, void* l) {
  __builtin_amdgcn_global_load_lds(
      (const __attribute__((address_space(1))) void*)g,
      (__attribute__((address_space(3))) void*)l, 16, 0, 0);
}

__device__ __forceinline__ unsigned short f2bf(float f) {
  unsigned int u = __builtin_bit_cast(unsigned int, f);
  unsigned int lsb = (u >> 16) & 1u;
  u += 0x7fffu + lsb;
  return (unsigned short)(u >> 16);
}

__device__ __forceinline__ float sani(float v) {
  return (v != v) ? 0.0f : fminf(fmaxf(v, -1e4f), 1e4f);
}

__global__ void prep_h(const float* __restrict__ h, unsigned short* __restrict__ hbf,
                       float* __restrict__ h0) {
  int m = blockIdx.x;
  int t = threadIdx.x;
  const float* row = h + (long)m * (K_TOT + 1);
  if (t == 0) h0[m] = sani(row[0]);
  unsigned short* dst = hbf + (long)m * K_TOT;
#pragma unroll
  for (int j = 0; j < 4; ++j) {
    int idx = t * 4 + j;
    dst[idx] = f2bf(sani(row[1 + idx]));
  }
}

__global__ void prep_w(const float* __restrict__ w, unsigned short* __restrict__ wbf,
                       float* __restrict__ wtime) {
  __shared__ float red[4];
  __shared__ float r_sh;
  int v = blockIdx.x;
  int t = threadIdx.x;
  const float* row = w + (long)v * K_TOT;
  float4 x = *(const float4*)(row + t * 4);
  float s = x.x * x.x + x.y * x.y + x.z * x.z + x.w * x.w;
#pragma unroll
  for (int off = 32; off > 0; off >>= 1) s += __shfl_down(s, off);
  int lane = t & 63, wv = t >> 6;
  if (lane == 0) red[wv] = s;
  __syncthreads();
  if (t == 0) {
    float tot = red[0] + red[1] + red[2] + red[3];
    float norm = sqrtf(tot);
    float r = (norm > 1e-7f) ? (sinhf(norm) / fmaxf(norm, 1e-7f)) : 1.0f;
    r_sh = r;
    wtime[v] = coshf(norm);
  }
  __syncthreads();
  float r = r_sh;
  ushort4 pack;
  pack.x = f2bf(r * x.x);
  pack.y = f2bf(r * x.y);
  pack.z = f2bf(r * x.z);
  pack.w = f2bf(r * x.w);
  *(ushort4*)(wbf + (long)v * K_TOT + t * 4) = pack;
}

// -------- 256x256 tile, BK=32, triple-buffered deep-prefetch GEMM ----------
// LDS: 3 buffers x 32KB: buf*32768 + mat*16384 + row*64 + chunk*16.
// While computing tile T (buf T%3): tile T+1 fully resident, tile T+2 being
// staged. One boundary per tile: vmcnt(4) (T+2's 4 loads stay in flight,
// proves T+1's 4 landed since they're 8-back) + s_barrier. No mid-tile waits;
// compiler handles ds_read->MFMA lgkmcnt (plain C++ loads).
// XOR swizzle (verified SQ_LDS_BANK_CONFLICT==0 in round 4/5): slot chunk c
// holds global chunk c ^ ((row>>1)&3); source pre-swizzled cc=(t&3)^((t>>3)&3);
// read chunk = fq ^ ((fr>>1)&3). Both sides, same involution (rule #21).
// Launch bounds (512,2): (512,4) caps VGPR at 64 -> acc spills -> 13.9GB HBM
// (round-4 disaster). Keep 2.
#define BAR __builtin_amdgcn_s_barrier()
#define VM4 asm volatile("s_waitcnt vmcnt(4)" ::: "memory")
#define RD8(off) (*(const short8*)(smem + (off)))

__global__ __launch_bounds__(512, 2) void gemm_geo(
    const unsigned short* __restrict__ hbf, const unsigned short* __restrict__ wbf,
    const float* __restrict__ h0, const float* __restrict__ wtime,
    const float* __restrict__ ls, float* __restrict__ out) {
  __shared__ __align__(16) char smem[98304];

  const int t = threadIdx.x;
  const int wave = t >> 6, lane = t & 63;
  const int fr = lane & 15, fq = lane >> 4;
  const int wm = wave >> 2, wn = wave & 3;  // 2 (M) x 4 (N) wave grid

  // XCD-bijective swizzle: 2000 blocks, 250/XCD; 16 consecutive blocks per
  // XCD share one B-panel (L2 reuse window).
  int bid = blockIdx.x;
  int swz = (bid & 7) * 250 + (bid >> 3);
  int tile_v = swz >> 4;
  int tile_m = swz & 15;
  int row0 = tile_m * 256;
  int col0 = tile_v * 256;

  // ds_read lane bases (bytes), + buf*32768 + mi*1024
  const int sw = (fq ^ ((fr >> 1) & 3)) * 16;
  const int a_rd = (wm * 128 + fr) * 64 + sw;
  const int b_rd = 16384 + (wn * 64 + fr) * 64 + sw;

  // stage: thread t covers (row = h*128 + t/4, slot chunk = t%3), global
  // chunk pre-swizzled
  const int cc = (t & 3) ^ ((t >> 3) & 3);
  const unsigned short* pA = hbf + (long)(row0 + (t >> 2)) * K_TOT + cc * 8;
  const unsigned short* pB = wbf + (long)(col0 + (t >> 2)) * K_TOT + cc * 8;
  const int dst_w = wave * 1024;  // wave-uniform; HW adds lane*16

  auto STAGE = [&](int kt, int d) {
#pragma unroll
    for (int h = 0; h < 2; ++h) {
      gload_lds16(pA + (long)h * 131072 + kt * 32,
                  smem + d * 32768 + h * 8192 + dst_w);
      gload_lds16(pB + (long)h * 131072 + kt * 32,
                  smem + d * 32768 + 16384 + h * 8192 + dst_w);
    }
  };

  f32x4 acc[8][4];
#pragma unroll
  for (int i = 0; i < 8; ++i)
#pragma unroll
    for (int j = 0; j < 4; ++j) acc[i][j] = (f32x4)(0.0f);

  // prologue: tiles 0,1 -> bufs 0,1 (8 loads); vmcnt(4): tile0 landed,
  // tile1 in flight.
  STAGE(0, 0);
  STAGE(1, 1);
  VM4;
  BAR;

  int cb = 0;  // compute buffer = kt % 3
#pragma unroll 1
  for (int kt = 0; kt < NKT; ++kt) {
    int sk = (kt + 2 < NKT) ? kt + 2 : NKT - 1;  // clamped redundant tail
    int sb = cb + 2;
    if (sb >= 3) sb -= 3;
    STAGE(sk, sb);  // 4 loads for tile kt+2

    short8 af[8], bf[4];
    int abase = a_rd + cb * 32768;
    int bbase = b_rd + cb * 32768;
#pragma unroll
    for (int mi = 0; mi < 8; ++mi) af[mi] = RD8(abase + mi * 1024);
#pragma unroll
    for (int ni = 0; ni < 4; ++ni) bf[ni] = RD8(bbase + ni * 1024);

    __builtin_amdgcn_s_setprio(1);
#pragma unroll
    for (int mi = 0; mi < 8; ++mi)
#pragma unroll
      for (int ni = 0; ni < 4; ++ni)
        acc[mi][ni] =
            __builtin_amdgcn_mfma_f32_16x16x32_bf16(af[mi], bf[ni], acc[mi][ni], 0, 0, 0);
    __builtin_amdgcn_s_setprio(0);

    // boundary: tile kt+1's loads (8 back) landed; tile kt+2's 4 stay in flight
    VM4;
    BAR;
    cb = (cb + 1 == 3) ? 0 : cb + 1;
  }

  // fused epilogue: x = h0*w_time - dot; d2 = safe_acosh(x)^2; out = -tau*d2
  float ntau = -fminf(fmaxf(ls[0], 0.01f), 2.5f);
  const float LN2 = 0.69314718055994531f;
  float wt[4];
#pragma unroll
  for (int ni = 0; ni < 4; ++ni) wt[ni] = wtime[col0 + wn * 64 + ni * 16 + fr];
#pragma unroll
  for (int mi = 0; mi < 8; ++mi) {
#pragma unroll
    for (int j = 0; j < 4; ++j) {
      int m = row0 + wm * 128 + mi * 16 + fq * 4 + j;
      float h0v = h0[m];
      float* orow = out + (long)m * V_TOT + col0 + wn * 64 + fr;
#pragma unroll
      for (int ni = 0; ni < 4; ++ni) {
        float dot = acc[mi][ni][j];
        float x = fmaf(h0v, wt[ni], -dot);
        float xm1 = fmaxf(x - 1.0f, 0.0f);
        float arg = fmaxf(fmaf(x, x, -1.0f), 0.0f);
        float lg2 = __builtin_amdgcn_logf(x + __builtin_amdgcn_sqrtf(arg));
        float dex = LN2 * lg2;
        float d2_exact = dex * dex;
        float ts = fmaf(xm1, -1.0f / 12.0f, 1.0f);
        float d2_tay = 2.0f * xm1 * ts * ts;
        float d2 = (xm1 < 1e-3f) ? d2_tay : d2_exact;
        __builtin_nontemporal_store(ntau * d2, &orow[ni * 16]);
      }
    }
  }
}

extern "C" void kernel_launch(void* const* d_in, const int* in_sizes, int n_in,
                              void* d_out, int out_size, void* d_ws, size_t ws_size,
                              hipStream_t stream) {
  const float* h = (const float*)d_in[0];   // [2,2048,1025]
  const float* w = (const float*)d_in[1];   // [32000,1024]
  const float* ls = (const float*)d_in[2];  // scalar
  float* out = (float*)d_out;               // [2,2048,32000] fp32

  char* ws = (char*)d_ws;
  unsigned short* wbf = (unsigned short*)ws;                  // 65,536,000 B
  unsigned short* hbf = (unsigned short*)(ws + 65536000);     // 8,388,608 B
  float* wtime = (float*)(ws + 65536000 + 8388608);           // 128,000 B
  float* h0 = (float*)(ws + 65536000 + 8388608 + 128000);     // 16,384 B

  prep_h<<<M_TOT, 256, 0, stream>>>(h, hbf, h0);
  prep_w<<<V_TOT, 256, 0, stream>>>(w, wbf, wtime);
  gemm_geo<<<2000, 512, 0, stream>>>(hbf, wbf, h0, wtime, ls, out);
}